// Round 6
// baseline (340.611 us; speedup 1.0000x reference)
//
#include <hip/hip_runtime.h>
#include <hip/hip_bf16.h>

typedef __bf16 bf16x8 __attribute__((ext_vector_type(8)));
typedef __bf16 bf16x4 __attribute__((ext_vector_type(4)));
typedef float  f32x4  __attribute__((ext_vector_type(4)));

// ---------------------------------------------------------------------------
// Kernel 1: prep (unchanged — validated)
// ---------------------------------------------------------------------------
__global__ __launch_bounds__(256) void prep_kernel(
    const float* __restrict__ img, const float* __restrict__ ques,
    const float* __restrict__ g_w1, const float* __restrict__ g_b1,
    const float* __restrict__ g_w2, const float* __restrict__ g_w3,
    const float* __restrict__ g_w4,
    float* __restrict__ U, float* __restrict__ V, float* __restrict__ Qb,
    __bf16* __restrict__ W2t, __bf16* __restrict__ W3t, __bf16* __restrict__ W4t) {
  __shared__ float smem[64 * 65];
  const int blk = blockIdx.x;
  const int t = threadIdx.x;

  if (blk < 256) {
    const int n = blk >> 2, obase = (blk & 3) * 16;
    for (int idx = t; idx < 66 * 16; idx += 256) {
      const int c = idx >> 4, o = obase + (idx & 15);
      float v;
      if (c < 64)      v = img[n * 4096 + c * 64 + o];
      else if (c == 64) v = (float)(o >> 3);
      else              v = (float)(o & 7);
      smem[idx] = v;
    }
    __syncthreads();
    float u[16], vv[16];
#pragma unroll
    for (int o = 0; o < 16; ++o) { u[o] = 0.f; vv[o] = 0.f; }
    for (int d = 0; d < 66; ++d) {
      const float wu = g_w1[d * 256 + t];
      const float wv = g_w1[(66 + d) * 256 + t];
#pragma unroll
      for (int o = 0; o < 16; ++o) {
        const float cc = smem[d * 16 + o];
        u[o]  += cc * wu;
        vv[o] += cc * wv;
      }
    }
#pragma unroll
    for (int o = 0; o < 16; ++o) {
      U[(size_t)(n * 64 + obase + o) * 256 + t] = u[o];
      V[(size_t)(n * 64 + obase + o) * 256 + t] = vv[o];
    }
  } else if (blk < 320) {
    const int n = blk - 256;
    smem[t] = ques[n * 256 + t];
    __syncthreads();
    float s = g_b1[t];
    for (int e = 0; e < 256; ++e) s += smem[e] * g_w1[(132 + e) * 256 + t];
    Qb[n * 256 + t] = s;
  } else {
    const int b2 = blk - 320;
    const int wsel = b2 >> 4;
    const int tile = b2 & 15;
    const int r0 = (tile >> 2) * 64, c0 = (tile & 3) * 64;
    const float* W = (wsel == 0) ? g_w2 : (wsel == 1) ? g_w3 : g_w4;
    __bf16* Wt    = (wsel == 0) ? W2t  : (wsel == 1) ? W3t  : W4t;
    const int col = t & 63, rb = (t >> 6) * 16;
#pragma unroll 4
    for (int j = 0; j < 16; ++j)
      smem[(rb + j) * 65 + col] = W[(size_t)(r0 + rb + j) * 256 + c0 + col];
    __syncthreads();
#pragma unroll 4
    for (int j = 0; j < 16; ++j)
      Wt[(size_t)(c0 + rb + j) * 256 + r0 + col] = (__bf16)smem[col * 65 + rb + j];
  }
}

// ---------------------------------------------------------------------------
// Kernel 2: fused g-MLP layers 2..4.
//  Block = 512 thr / 8 waves, handles TWO (n,i) objects:
//   half h (waves 4h..4h+3) owns slab h (32 KB), object i0+h.
//   Wave = 64 rows x 64-col strip: acc 4x4 f32x4 (64 VGPR), MFMA:ds_read 4:1.
//  Single-buffered B (no ring) -> nominal ~118 regs, fits 128 cap
//   (__launch_bounds__(512,4)) -> 2 blocks/CU = 16 waves, 2 barrier groups.
//  Slab elem(row,c) = (c>>3)*512 + ((row+(c>>3))&63)*8 + (c&7)
// ---------------------------------------------------------------------------
#define HSZ 16384   // bf16 elems per slab (32 KB)

__device__ __forceinline__ int hidx(int row, int c) {
  const int kb = c >> 3;
  return kb * 512 + (((row + kb) & 63) << 3) + (c & 7);
}

template <bool LAST>
__device__ __forceinline__ void g_layer(__bf16* Hs,
                                        const __bf16* __restrict__ wbase,
                                        const float* __restrict__ bias_g,
                                        int ws, int q, int r16,
                                        float* __restrict__ part_row) {
  f32x4 acc[4][4];
  const f32x4 z = {0.f, 0.f, 0.f, 0.f};
#pragma unroll
  for (int m = 0; m < 4; ++m)
#pragma unroll
    for (int nt = 0; nt < 4; ++nt) acc[m][nt] = z;

#pragma unroll
  for (int ks = 0; ks < 8; ++ks) {
    bf16x8 b[4];
#pragma unroll
    for (int nt = 0; nt < 4; ++nt)
      b[nt] = *(const bf16x8*)(wbase + nt * 4096 + ks * 32);
    const int kb = ks * 4 + q;
    bf16x8 a[4];
#pragma unroll
    for (int m = 0; m < 4; ++m) {
      const int row = m * 16 + r16;
      a[m] = *(const bf16x8*)(&Hs[kb * 512 + (((row + kb) & 63) << 3)]);
    }
#pragma unroll
    for (int m = 0; m < 4; ++m)
#pragma unroll
      for (int nt = 0; nt < 4; ++nt)
        // swapped operands (validated): acc[m][nt] -> row m*16+r16,
        // cols ws*64 + nt*16 + q*4 + reg
        acc[m][nt] = __builtin_amdgcn_mfma_f32_16x16x32_bf16(b[nt], a[m], acc[m][nt], 0, 0, 0);
  }

  f32x4 bv[4];
#pragma unroll
  for (int nt = 0; nt < 4; ++nt)
    bv[nt] = *(const f32x4*)&bias_g[ws * 64 + nt * 16 + q * 4];

  if (!LAST) {
    __syncthreads();   // all waves done reading slabs
#pragma unroll
    for (int m = 0; m < 4; ++m)
#pragma unroll
      for (int nt = 0; nt < 4; ++nt) {
        const int cb = ws * 64 + nt * 16 + q * 4;
        const f32x4 s = acc[m][nt] + bv[nt];
        bf16x4 h;
#pragma unroll
        for (int r = 0; r < 4; ++r) h[r] = (__bf16)fmaxf(s[r], 0.f);
        *(bf16x4*)(&Hs[hidx(m * 16 + r16, cb)]) = h;
      }
    __syncthreads();
  } else {
    // wave owns distinct cols: reduce rows in-thread (m) then across r16 lanes
#pragma unroll
    for (int nt = 0; nt < 4; ++nt) {
      const int cb = ws * 64 + nt * 16 + q * 4;
      f32x4 s;
#pragma unroll
      for (int r = 0; r < 4; ++r)
        s[r] = fmaxf(acc[0][nt][r] + bv[nt][r], 0.f)
             + fmaxf(acc[1][nt][r] + bv[nt][r], 0.f)
             + fmaxf(acc[2][nt][r] + bv[nt][r], 0.f)
             + fmaxf(acc[3][nt][r] + bv[nt][r], 0.f);
#pragma unroll
      for (int d = 1; d < 16; d <<= 1) {
#pragma unroll
        for (int r = 0; r < 4; ++r) s[r] += __shfl_xor(s[r], d, 64);
      }
      if (r16 == 0) *(f32x4*)&part_row[cb] = s;
    }
  }
}

__global__ __launch_bounds__(512, 4) void rn_main(
    const float* __restrict__ U, const float* __restrict__ V,
    const float* __restrict__ Qb,
    const __bf16* __restrict__ Wt,   // W2t; W3t = +65536, W4t = +131072 elems
    const float* __restrict__ b2, const float* __restrict__ b3,
    const float* __restrict__ b4,
    float* __restrict__ part) {
  __shared__ __align__(16) __bf16 Hs[2 * HSZ];   // two 32 KB slabs
  const int blk = blockIdx.x;                    // 2048 blocks
  const int nimg = blk >> 5;
  const int i0 = (blk & 31) * 2;
  const int t = threadIdx.x;
  const int half = t >> 8;                       // which object / slab
  const int iobj = i0 + half;
  const int tt = t & 255;
  const int ws = tt >> 6;                        // 64-col strip
  const int lane = t & 63;
  const int q = lane >> 4, r16 = lane & 15;

  __bf16* slab = Hs + half * HSZ;

  // phase 0: h1[j][:] = relu(U[n,i,:] + V[n,j,:] + Qb[n,:]) -> own slab
  {
    const int c4 = tt & 63;          // col-quad: cols 4*c4..4*c4+3
    const int jb = (tt >> 6) * 16;   // 16 rows per thread
    const f32x4 u4 = *(const f32x4*)&U[(size_t)(nimg * 64 + iobj) * 256 + c4 * 4];
    const f32x4 q4 = *(const f32x4*)&Qb[(size_t)nimg * 256 + c4 * 4];
    const f32x4 uq = u4 + q4;
#pragma unroll
    for (int jj = 0; jj < 16; ++jj) {
      const int row = jb + jj;
      const f32x4 v4 = *(const f32x4*)&V[(size_t)(nimg * 64 + row) * 256 + c4 * 4];
      bf16x4 h;
#pragma unroll
      for (int r = 0; r < 4; ++r) h[r] = (__bf16)fmaxf(uq[r] + v4[r], 0.f);
      *(bf16x4*)(&slab[hidx(row, c4 * 4)]) = h;
    }
  }
  __syncthreads();

  // lane-resolved weight base: row (output col) = ws*64 + nt*16 + r16, K off q*8
  const __bf16* wb = Wt + (size_t)(ws * 64 + r16) * 256 + q * 8;
  float* part_row = part + (size_t)(nimg * 64 + iobj) * 256;

  g_layer<false>(slab, wb,          b2, ws, q, r16, part_row);
  g_layer<false>(slab, wb +  65536, b3, ws, q, r16, part_row);
  g_layer<true >(slab, wb + 131072, b4, ws, q, r16, part_row);
}

// ---------------------------------------------------------------------------
// Kernel 3: reduce partials -> context, f-MLP (fp32), log_softmax
// ---------------------------------------------------------------------------
__global__ __launch_bounds__(256) void rn_final(
    const float* __restrict__ part,
    const float* __restrict__ f_w1, const float* __restrict__ f_b1,
    const float* __restrict__ f_w2, const float* __restrict__ f_b2,
    const float* __restrict__ f_w3, const float* __restrict__ f_b3,
    float* __restrict__ out) {
  __shared__ float ctx[256], y1[256], y2[256], sc[2];
  const int n = blockIdx.x, t = threadIdx.x;

  float s = 0.f;
  for (int i = 0; i < 64; ++i) s += part[((size_t)n * 64 + i) * 256 + t];
  ctx[t] = s * (1.0f / 4096.0f);
  __syncthreads();

  float a = f_b1[t];
  for (int k = 0; k < 256; ++k) a += ctx[k] * f_w1[k * 256 + t];
  y1[t] = fmaxf(a, 0.f);
  __syncthreads();

  float b = f_b2[t];
  for (int k = 0; k < 256; ++k) b += y1[k] * f_w2[k * 256 + t];
  y2[t] = fmaxf(b, 0.f);
  __syncthreads();

  if (t < 2) {
    float c = f_b3[t];
    for (int k = 0; k < 256; ++k) c += y2[k] * f_w3[k * 2 + t];
    sc[t] = c;
  }
  __syncthreads();

  if (t == 0) {
    const float s0 = sc[0], s1 = sc[1];
    const float mx = fmaxf(s0, s1);
    const float lse = mx + logf(expf(s0 - mx) + expf(s1 - mx));
    out[n * 2 + 0] = s0 - lse;
    out[n * 2 + 1] = s1 - lse;
  }
}

// ---------------------------------------------------------------------------
extern "C" void kernel_launch(void* const* d_in, const int* in_sizes, int n_in,
                              void* d_out, int out_size, void* d_ws, size_t ws_size,
                              hipStream_t stream) {
  const float* img  = (const float*)d_in[0];
  const float* ques = (const float*)d_in[1];
  const float* g_w1 = (const float*)d_in[2];
  const float* g_b1 = (const float*)d_in[3];
  const float* g_w2 = (const float*)d_in[4];
  const float* g_b2 = (const float*)d_in[5];
  const float* g_w3 = (const float*)d_in[6];
  const float* g_b3 = (const float*)d_in[7];
  const float* g_w4 = (const float*)d_in[8];
  const float* g_b4 = (const float*)d_in[9];
  const float* f_w1 = (const float*)d_in[10];
  const float* f_b1 = (const float*)d_in[11];
  const float* f_w2 = (const float*)d_in[12];
  const float* f_b2 = (const float*)d_in[13];
  const float* f_w3 = (const float*)d_in[14];
  const float* f_b3 = (const float*)d_in[15];
  float* out = (float*)d_out;

  char* ws = (char*)d_ws;
  float*  U    = (float*)(ws);                                 // 4 MB
  float*  V    = (float*)(ws + (size_t)4  * 1048576);          // 4 MB
  float*  part = (float*)(ws + (size_t)8  * 1048576);          // 4 MB
  float*  Qb   = (float*)(ws + (size_t)12 * 1048576);          // 64 KB
  __bf16* W2t  = (__bf16*)(ws + (size_t)12 * 1048576 + 65536); // contiguous
  __bf16* W3t  = W2t + 65536;
  __bf16* W4t  = W3t + 65536;

  prep_kernel<<<368, 256, 0, stream>>>(img, ques, g_w1, g_b1, g_w2, g_w3, g_w4,
                                       U, V, Qb, W2t, W3t, W4t);
  rn_main<<<2048, 512, 0, stream>>>(U, V, Qb, W2t, g_b2, g_b3, g_b4, part);
  rn_final<<<64, 256, 0, stream>>>(part, f_w1, f_b1, f_w2, f_b2, f_w3, f_b3, out);
}

// Round 7
// 312.556 us; speedup vs baseline: 1.0898x; 1.0898x over previous
//
#include <hip/hip_runtime.h>
#include <hip/hip_bf16.h>

typedef __bf16 bf16x8 __attribute__((ext_vector_type(8)));
typedef __bf16 bf16x4 __attribute__((ext_vector_type(4)));
typedef float  f32x4  __attribute__((ext_vector_type(4)));

// ---------------------------------------------------------------------------
// Kernel 1: prep (unchanged — validated)
// ---------------------------------------------------------------------------
__global__ __launch_bounds__(256) void prep_kernel(
    const float* __restrict__ img, const float* __restrict__ ques,
    const float* __restrict__ g_w1, const float* __restrict__ g_b1,
    const float* __restrict__ g_w2, const float* __restrict__ g_w3,
    const float* __restrict__ g_w4,
    float* __restrict__ U, float* __restrict__ V, float* __restrict__ Qb,
    __bf16* __restrict__ W2t, __bf16* __restrict__ W3t, __bf16* __restrict__ W4t) {
  __shared__ float smem[64 * 65];
  const int blk = blockIdx.x;
  const int t = threadIdx.x;

  if (blk < 256) {
    const int n = blk >> 2, obase = (blk & 3) * 16;
    for (int idx = t; idx < 66 * 16; idx += 256) {
      const int c = idx >> 4, o = obase + (idx & 15);
      float v;
      if (c < 64)      v = img[n * 4096 + c * 64 + o];
      else if (c == 64) v = (float)(o >> 3);
      else              v = (float)(o & 7);
      smem[idx] = v;
    }
    __syncthreads();
    float u[16], vv[16];
#pragma unroll
    for (int o = 0; o < 16; ++o) { u[o] = 0.f; vv[o] = 0.f; }
    for (int d = 0; d < 66; ++d) {
      const float wu = g_w1[d * 256 + t];
      const float wv = g_w1[(66 + d) * 256 + t];
#pragma unroll
      for (int o = 0; o < 16; ++o) {
        const float cc = smem[d * 16 + o];
        u[o]  += cc * wu;
        vv[o] += cc * wv;
      }
    }
#pragma unroll
    for (int o = 0; o < 16; ++o) {
      U[(size_t)(n * 64 + obase + o) * 256 + t] = u[o];
      V[(size_t)(n * 64 + obase + o) * 256 + t] = vv[o];
    }
  } else if (blk < 320) {
    const int n = blk - 256;
    smem[t] = ques[n * 256 + t];
    __syncthreads();
    float s = g_b1[t];
    for (int e = 0; e < 256; ++e) s += smem[e] * g_w1[(132 + e) * 256 + t];
    Qb[n * 256 + t] = s;
  } else {
    const int b2 = blk - 320;
    const int wsel = b2 >> 4;
    const int tile = b2 & 15;
    const int r0 = (tile >> 2) * 64, c0 = (tile & 3) * 64;
    const float* W = (wsel == 0) ? g_w2 : (wsel == 1) ? g_w3 : g_w4;
    __bf16* Wt    = (wsel == 0) ? W2t  : (wsel == 1) ? W3t  : W4t;
    const int col = t & 63, rb = (t >> 6) * 16;
#pragma unroll 4
    for (int j = 0; j < 16; ++j)
      smem[(rb + j) * 65 + col] = W[(size_t)(r0 + rb + j) * 256 + c0 + col];
    __syncthreads();
#pragma unroll 4
    for (int j = 0; j < 16; ++j)
      Wt[(size_t)(c0 + rb + j) * 256 + r0 + col] = (__bf16)smem[col * 65 + rb + j];
  }
}

// ---------------------------------------------------------------------------
// Kernel 2: fused g-MLP layers 2..4. 256 thr / 4 waves, one (n,i) per block.
//  Wave ws owns ALL 64 rows x 64-col strip: acc 4x4 f32x4.
//  NOTE gfx950 unified VGPR/AGPR file: true register demand = acc(64, AGPR)
//  + arch VGPRs (~80) ≈ 150. __launch_bounds__(256,3) -> cap ~170: NO SPILL
//  (rounds 5/6 capped at 128 and spilled ~34 dwords/thread -> 139 MB writes).
//  3 blocks/CU co-resident (96 KB LDS) = 3 independent barrier groups.
//  Slab elem(row,c) = (c>>3)*512 + ((row+(c>>3))&63)*8 + (c&7)
// ---------------------------------------------------------------------------
#define HSZ 16384   // bf16 elems per slab (32 KB)

__device__ __forceinline__ int hidx(int row, int c) {
  const int kb = c >> 3;
  return kb * 512 + (((row + kb) & 63) << 3) + (c & 7);
}

template <bool LAST>
__device__ __forceinline__ void g_layer(__bf16* Hs,
                                        const __bf16* __restrict__ wbase,
                                        const float* __restrict__ bias_g,
                                        int ws, int q, int r16,
                                        float* __restrict__ part_row) {
  f32x4 acc[4][4];
  const f32x4 z = {0.f, 0.f, 0.f, 0.f};
#pragma unroll
  for (int m = 0; m < 4; ++m)
#pragma unroll
    for (int nt = 0; nt < 4; ++nt) acc[m][nt] = z;

#pragma unroll
  for (int ks = 0; ks < 8; ++ks) {
    bf16x8 b[4];
#pragma unroll
    for (int nt = 0; nt < 4; ++nt)
      b[nt] = *(const bf16x8*)(wbase + nt * 4096 + ks * 32);
    const int kb = ks * 4 + q;
    bf16x8 a[4];
#pragma unroll
    for (int m = 0; m < 4; ++m) {
      const int row = m * 16 + r16;
      a[m] = *(const bf16x8*)(&Hs[kb * 512 + (((row + kb) & 63) << 3)]);
    }
#pragma unroll
    for (int m = 0; m < 4; ++m)
#pragma unroll
      for (int nt = 0; nt < 4; ++nt)
        // swapped operands (validated): acc[m][nt] -> row m*16+r16,
        // cols ws*64 + nt*16 + q*4 + reg
        acc[m][nt] = __builtin_amdgcn_mfma_f32_16x16x32_bf16(b[nt], a[m], acc[m][nt], 0, 0, 0);
  }

  f32x4 bv[4];
#pragma unroll
  for (int nt = 0; nt < 4; ++nt)
    bv[nt] = *(const f32x4*)&bias_g[ws * 64 + nt * 16 + q * 4];

  if (!LAST) {
    __syncthreads();   // all waves done reading slab
#pragma unroll
    for (int m = 0; m < 4; ++m)
#pragma unroll
      for (int nt = 0; nt < 4; ++nt) {
        const int cb = ws * 64 + nt * 16 + q * 4;
        const f32x4 s = acc[m][nt] + bv[nt];
        bf16x4 h;
#pragma unroll
        for (int r = 0; r < 4; ++r) h[r] = (__bf16)fmaxf(s[r], 0.f);
        *(bf16x4*)(&Hs[hidx(m * 16 + r16, cb)]) = h;
      }
    __syncthreads();
  } else {
    // wave owns distinct cols: reduce rows in-thread (m) then across r16 lanes
#pragma unroll
    for (int nt = 0; nt < 4; ++nt) {
      const int cb = ws * 64 + nt * 16 + q * 4;
      f32x4 s;
#pragma unroll
      for (int r = 0; r < 4; ++r)
        s[r] = fmaxf(acc[0][nt][r] + bv[nt][r], 0.f)
             + fmaxf(acc[1][nt][r] + bv[nt][r], 0.f)
             + fmaxf(acc[2][nt][r] + bv[nt][r], 0.f)
             + fmaxf(acc[3][nt][r] + bv[nt][r], 0.f);
#pragma unroll
      for (int d = 1; d < 16; d <<= 1) {
#pragma unroll
        for (int r = 0; r < 4; ++r) s[r] += __shfl_xor(s[r], d, 64);
      }
      if (r16 == 0) *(f32x4*)&part_row[cb] = s;
    }
  }
}

__global__ __launch_bounds__(256, 3) void rn_main(
    const float* __restrict__ U, const float* __restrict__ V,
    const float* __restrict__ Qb,
    const __bf16* __restrict__ Wt,   // W2t; W3t = +65536, W4t = +131072 elems
    const float* __restrict__ b2, const float* __restrict__ b3,
    const float* __restrict__ b4,
    float* __restrict__ part) {
  __shared__ __align__(16) __bf16 Hs[HSZ];   // 32 KB
  const int blk = blockIdx.x;
  const int nimg = blk >> 6, iobj = blk & 63;
  const int t = threadIdx.x;
  const int ws = t >> 6, lane = t & 63;
  const int q = lane >> 4, r16 = lane & 15;

  // phase 0: h1[j][:] = relu(U[n,i,:] + V[n,j,:] + Qb[n,:]) -> Hs
  {
    const int c4 = t & 63;          // col-quad: cols 4*c4..4*c4+3
    const int jb = (t >> 6) * 16;   // 16 rows per thread
    const f32x4 u4 = *(const f32x4*)&U[(size_t)(nimg * 64 + iobj) * 256 + c4 * 4];
    const f32x4 q4 = *(const f32x4*)&Qb[(size_t)nimg * 256 + c4 * 4];
    const f32x4 uq = u4 + q4;
#pragma unroll
    for (int jj = 0; jj < 16; ++jj) {
      const int row = jb + jj;
      const f32x4 v4 = *(const f32x4*)&V[(size_t)(nimg * 64 + row) * 256 + c4 * 4];
      bf16x4 h;
#pragma unroll
      for (int r = 0; r < 4; ++r) h[r] = (__bf16)fmaxf(uq[r] + v4[r], 0.f);
      *(bf16x4*)(&Hs[hidx(row, c4 * 4)]) = h;
    }
  }
  __syncthreads();

  // lane-resolved weight base: row (output col) = ws*64 + nt*16 + r16, K off q*8
  const __bf16* wb = Wt + (size_t)(ws * 64 + r16) * 256 + q * 8;
  float* part_row = part + (size_t)blk * 256;

  g_layer<false>(Hs, wb,          b2, ws, q, r16, part_row);
  g_layer<false>(Hs, wb +  65536, b3, ws, q, r16, part_row);
  g_layer<true >(Hs, wb + 131072, b4, ws, q, r16, part_row);
}

// ---------------------------------------------------------------------------
// Kernel 3: reduce partials -> context, f-MLP (fp32), log_softmax
// ---------------------------------------------------------------------------
__global__ __launch_bounds__(256) void rn_final(
    const float* __restrict__ part,
    const float* __restrict__ f_w1, const float* __restrict__ f_b1,
    const float* __restrict__ f_w2, const float* __restrict__ f_b2,
    const float* __restrict__ f_w3, const float* __restrict__ f_b3,
    float* __restrict__ out) {
  __shared__ float ctx[256], y1[256], y2[256], sc[2];
  const int n = blockIdx.x, t = threadIdx.x;

  float s = 0.f;
  for (int i = 0; i < 64; ++i) s += part[((size_t)n * 64 + i) * 256 + t];
  ctx[t] = s * (1.0f / 4096.0f);
  __syncthreads();

  float a = f_b1[t];
  for (int k = 0; k < 256; ++k) a += ctx[k] * f_w1[k * 256 + t];
  y1[t] = fmaxf(a, 0.f);
  __syncthreads();

  float b = f_b2[t];
  for (int k = 0; k < 256; ++k) b += y1[k] * f_w2[k * 256 + t];
  y2[t] = fmaxf(b, 0.f);
  __syncthreads();

  if (t < 2) {
    float c = f_b3[t];
    for (int k = 0; k < 256; ++k) c += y2[k] * f_w3[k * 2 + t];
    sc[t] = c;
  }
  __syncthreads();

  if (t == 0) {
    const float s0 = sc[0], s1 = sc[1];
    const float mx = fmaxf(s0, s1);
    const float lse = mx + logf(expf(s0 - mx) + expf(s1 - mx));
    out[n * 2 + 0] = s0 - lse;
    out[n * 2 + 1] = s1 - lse;
  }
}

// ---------------------------------------------------------------------------
extern "C" void kernel_launch(void* const* d_in, const int* in_sizes, int n_in,
                              void* d_out, int out_size, void* d_ws, size_t ws_size,
                              hipStream_t stream) {
  const float* img  = (const float*)d_in[0];
  const float* ques = (const float*)d_in[1];
  const float* g_w1 = (const float*)d_in[2];
  const float* g_b1 = (const float*)d_in[3];
  const float* g_w2 = (const float*)d_in[4];
  const float* g_b2 = (const float*)d_in[5];
  const float* g_w3 = (const float*)d_in[6];
  const float* g_b3 = (const float*)d_in[7];
  const float* g_w4 = (const float*)d_in[8];
  const float* g_b4 = (const float*)d_in[9];
  const float* f_w1 = (const float*)d_in[10];
  const float* f_b1 = (const float*)d_in[11];
  const float* f_w2 = (const float*)d_in[12];
  const float* f_b2 = (const float*)d_in[13];
  const float* f_w3 = (const float*)d_in[14];
  const float* f_b3 = (const float*)d_in[15];
  float* out = (float*)d_out;

  char* ws = (char*)d_ws;
  float*  U    = (float*)(ws);                                 // 4 MB
  float*  V    = (float*)(ws + (size_t)4  * 1048576);          // 4 MB
  float*  part = (float*)(ws + (size_t)8  * 1048576);          // 4 MB
  float*  Qb   = (float*)(ws + (size_t)12 * 1048576);          // 64 KB
  __bf16* W2t  = (__bf16*)(ws + (size_t)12 * 1048576 + 65536); // contiguous
  __bf16* W3t  = W2t + 65536;
  __bf16* W4t  = W3t + 65536;

  prep_kernel<<<368, 256, 0, stream>>>(img, ques, g_w1, g_b1, g_w2, g_w3, g_w4,
                                       U, V, Qb, W2t, W3t, W4t);
  rn_main<<<4096, 256, 0, stream>>>(U, V, Qb, W2t, g_b2, g_b3, g_b4, part);
  rn_final<<<64, 256, 0, stream>>>(part, f_w1, f_b1, f_w2, f_b2, f_w3, f_b3, out);
}